// Round 10
// baseline (2683.773 us; speedup 1.0000x reference)
//
#include <hip/hip_runtime.h>
#include <hip/hip_cooperative_groups.h>
#include <stdint.h>

namespace cg = cooperative_groups;

#define VOCABN 32000
#define EMBEDN 256
#define HIDN   512
#define BN     64
#define SOSID  1
#define EOSID  2
#define NSUB   8    // argmax sub-slots to spread atomic contention
#define NBLK   500  // cooperative grid size (<= 512 co-resident at 2 blocks/CU)
#define GHBLK  128

typedef __attribute__((ext_vector_type(8))) short short8;
typedef __attribute__((ext_vector_type(4))) float f32x4;

// ---------- helpers ----------
__device__ __forceinline__ unsigned ordf(float f) {
  unsigned u = __float_as_uint(f);
  return (u & 0x80000000u) ? ~u : (u | 0x80000000u);
}
__device__ __forceinline__ int decode_pred(unsigned long long pk) {
  return (int)(0xFFFFFFFFu - (unsigned)(pk & 0xFFFFFFFFull));
}
__device__ __forceinline__ unsigned short f2bf(float x) {  // RNE f32->bf16
  unsigned u = __float_as_uint(x);
  unsigned r = (u + 0x7FFFu + ((u >> 16) & 1u)) >> 16;
  return (unsigned short)r;
}
__device__ __forceinline__ float bf2f(unsigned short h) {
  return __uint_as_float(((unsigned)h) << 16);
}
// acc += Ahi*Bhi + Ahi*Blo + Alo*Bhi   (bf16x3 split product)
__device__ __forceinline__ f32x4 mfma3(short8 ah, short8 al, short8 bh, short8 bl,
                                       f32x4 acc) {
  acc = __builtin_amdgcn_mfma_f32_16x16x32_bf16(ah, bh, acc, 0, 0, 0);
  acc = __builtin_amdgcn_mfma_f32_16x16x32_bf16(ah, bl, acc, 0, 0, 0);
  acc = __builtin_amdgcn_mfma_f32_16x16x32_bf16(al, bh, acc, 0, 0, 0);
  return acc;
}

// ---------- init: h0 = mean(features), fp32 + bf16 hi/lo fragment split ----------
__global__ void k_init(const float* __restrict__ feat, float* __restrict__ h0,
                       int L, int* __restrict__ done, char* __restrict__ Hsp0) {
  int b = blockIdx.x, tid = threadIdx.x;
  float inv = 1.0f / (float)L;
  for (int j = tid; j < HIDN; j += 256) {
    const float* p = feat + (size_t)b * L * HIDN + j;
    float s = 0.f;
    for (int l = 0; l < L; ++l) s += p[(size_t)l * HIDN];
    float hv = s * inv;
    h0[b * HIDN + j] = hv;
    unsigned short hi = f2bf(hv);
    unsigned short lo = f2bf(hv - bf2f(hi));
    int bt = b >> 4, col = b & 15, kt = j >> 5, kr = j & 31;
    int ln = ((kr >> 3) << 4) | col, e = kr & 7;
    size_t off = (size_t)(bt * 16 + kt) * 2048 + ln * 16 + e * 2;
    *(unsigned short*)(Hsp0 + off) = hi;
    *(unsigned short*)(Hsp0 + off + 1024) = lo;
  }
  if (b == 0 && tid < 2 * BN) done[tid] = 0;
}

// ---------- generic W split into MFMA-fragment-ordered bf16 hi/lo tiles ----------
__global__ __launch_bounds__(256) void k_splitW(const float* __restrict__ W,
                                                char* __restrict__ Wsp,
                                                int ktshift, int K) {
  int tid = threadIdx.x, lane = tid & 63, tl = tid >> 6;
  int tile = blockIdx.x * 4 + tl;
  int vt = tile >> ktshift, kt = tile & ((1 << ktshift) - 1);
  int v = vt * 16 + (lane & 15);
  int k0 = kt * 32 + ((lane >> 4) << 3);
  const float* src = W + (size_t)v * K + k0;
  float xv[8];
  *(float4*)&xv[0] = *(const float4*)src;
  *(float4*)&xv[4] = *(const float4*)(src + 4);
  unsigned short h[8], l[8];
  #pragma unroll
  for (int i = 0; i < 8; ++i) {
    h[i] = f2bf(xv[i]);
    l[i] = f2bf(xv[i] - bf2f(h[i]));
  }
  uint4 H, Lw;
  H.x = (unsigned)h[0] | ((unsigned)h[1] << 16);
  H.y = (unsigned)h[2] | ((unsigned)h[3] << 16);
  H.z = (unsigned)h[4] | ((unsigned)h[5] << 16);
  H.w = (unsigned)h[6] | ((unsigned)h[7] << 16);
  Lw.x = (unsigned)l[0] | ((unsigned)l[1] << 16);
  Lw.y = (unsigned)l[2] | ((unsigned)l[3] << 16);
  Lw.z = (unsigned)l[4] | ((unsigned)l[5] << 16);
  Lw.w = (unsigned)l[6] | ((unsigned)l[7] << 16);
  char* dst = Wsp + (size_t)tile * 2048 + lane * 16;
  *(uint4*)dst = H;
  *(uint4*)(dst + 1024) = Lw;
}

// ---------- gh phase body (identical math to r7 k_gh) ----------
__device__ __forceinline__ void gh_body(
    int bid, int tid, int lane, int wid, char* lds,
    const float* __restrict__ emb, const char* __restrict__ Wihsp,
    const char* __restrict__ Whhsp, const float* __restrict__ b_ih,
    const float* __restrict__ b_hh, const float* __restrict__ h_rd,
    float* __restrict__ h_wr, const char* __restrict__ Hsp_rd,
    char* __restrict__ Hsp_wr, const unsigned long long* __restrict__ s_rd,
    unsigned long long* __restrict__ s_wr, const int* __restrict__ done_rd,
    int* __restrict__ done_wr, float* __restrict__ out_toks, int t, int T) {
  int* preds = (int*)lds;                                   // 16 ints
  float (*red)[4][256] = (float (*)[4][256])(lds + 64);     // [3][4][256]
  int jt = bid >> 2, bt = bid & 3;

  if (tid < 16) {
    int pr = SOSID;
    if (t) {
      unsigned long long mx = 0ull;
      #pragma unroll
      for (int s = 0; s < NSUB; ++s) {
        unsigned long long v = s_rd[s * BN + bt * 16 + tid];
        mx = (v > mx) ? v : mx;
      }
      pr = decode_pred(mx);
    }
    preds[tid] = pr;
  }
  if (bid == 0) {
    s_wr[tid] = 0ull;
    s_wr[256 + tid] = 0ull;
    if (t >= 1 && tid < BN) {
      unsigned long long mx = 0ull;
      #pragma unroll
      for (int s = 0; s < NSUB; ++s) {
        unsigned long long v = s_rd[s * BN + tid];
        mx = (v > mx) ? v : mx;
      }
      int pred = decode_pred(mx);
      int iseos = (pred == EOSID) ? 1 : 0;
      int dold = done_rd[tid];
      out_toks[(size_t)tid * T + (t - 1)] = (float)((dold | iseos) ? 0 : pred);
      done_wr[tid] = dold | iseos;
    }
  }
  __syncthreads();

  int col = lane & 15, rg = lane >> 4;
  int xrow = preds[col];
  f32x4 acc_r = {0.f, 0.f, 0.f, 0.f}, acc_z = {0.f, 0.f, 0.f, 0.f};
  f32x4 acc_gin = {0.f, 0.f, 0.f, 0.f}, acc_ghn = {0.f, 0.f, 0.f, 0.f};

  #pragma unroll
  for (int u = 0; u < 6; ++u) {
    int g = wid * 6 + u;
    if (g < 8) {
      float xv[8];
      const float* src = emb + (size_t)xrow * EMBEDN + g * 32 + rg * 8;
      *(float4*)&xv[0] = *(const float4*)src;
      *(float4*)&xv[4] = *(const float4*)(src + 4);
      short8 xh, xl;
      #pragma unroll
      for (int i = 0; i < 8; ++i) {
        unsigned short h = f2bf(xv[i]);
        xh[i] = (short)h;
        xl[i] = (short)f2bf(xv[i] - bf2f(h));
      }
      const char* pr_ = Wihsp + (size_t)((jt) * 8 + g) * 2048 + lane * 16;
      const char* pz_ = Wihsp + (size_t)((32 + jt) * 8 + g) * 2048 + lane * 16;
      const char* pn_ = Wihsp + (size_t)((64 + jt) * 8 + g) * 2048 + lane * 16;
      acc_r = mfma3(*(const short8*)pr_, *(const short8*)(pr_ + 1024), xh, xl, acc_r);
      acc_z = mfma3(*(const short8*)pz_, *(const short8*)(pz_ + 1024), xh, xl, acc_z);
      acc_gin = mfma3(*(const short8*)pn_, *(const short8*)(pn_ + 1024), xh, xl, acc_gin);
    } else {
      int kt = g - 8;
      const char* bq = Hsp_rd + (size_t)(bt * 16 + kt) * 2048 + lane * 16;
      short8 hh = *(const short8*)bq;
      short8 hl = *(const short8*)(bq + 1024);
      const char* pr_ = Whhsp + (size_t)((jt) * 16 + kt) * 2048 + lane * 16;
      const char* pz_ = Whhsp + (size_t)((32 + jt) * 16 + kt) * 2048 + lane * 16;
      const char* pn_ = Whhsp + (size_t)((64 + jt) * 16 + kt) * 2048 + lane * 16;
      acc_r = mfma3(*(const short8*)pr_, *(const short8*)(pr_ + 1024), hh, hl, acc_r);
      acc_z = mfma3(*(const short8*)pz_, *(const short8*)(pz_ + 1024), hh, hl, acc_z);
      acc_ghn = mfma3(*(const short8*)pn_, *(const short8*)(pn_ + 1024), hh, hl, acc_ghn);
    }
  }

  if (wid) {
    *(f32x4*)&red[wid - 1][0][lane * 4] = acc_r;
    *(f32x4*)&red[wid - 1][1][lane * 4] = acc_z;
    *(f32x4*)&red[wid - 1][2][lane * 4] = acc_gin;
    *(f32x4*)&red[wid - 1][3][lane * 4] = acc_ghn;
  }
  __syncthreads();
  if (wid == 0) {
    #pragma unroll
    for (int w = 0; w < 3; ++w) {
      acc_r += *(f32x4*)&red[w][0][lane * 4];
      acc_z += *(f32x4*)&red[w][1][lane * 4];
      acc_gin += *(f32x4*)&red[w][2][lane * 4];
      acc_ghn += *(f32x4*)&red[w][3][lane * 4];
    }
    int j = jt * 16 + rg * 4;
    int b = bt * 16 + col;
    float4 bir = *(const float4*)(b_ih + j);
    float4 bhr = *(const float4*)(b_hh + j);
    float4 biz = *(const float4*)(b_ih + 512 + j);
    float4 bhz = *(const float4*)(b_hh + 512 + j);
    float4 bin = *(const float4*)(b_ih + 1024 + j);
    float4 bhn = *(const float4*)(b_hh + 1024 + j);
    float bra[4] = {bir.x + bhr.x, bir.y + bhr.y, bir.z + bhr.z, bir.w + bhr.w};
    float bza[4] = {biz.x + bhz.x, biz.y + bhz.y, biz.z + bhz.z, biz.w + bhz.w};
    float bia[4] = {bin.x, bin.y, bin.z, bin.w};
    float bha[4] = {bhn.x, bhn.y, bhn.z, bhn.w};
    float4 hold4 = *(const float4*)(h_rd + (size_t)b * HIDN + j);
    float ho[4] = {hold4.x, hold4.y, hold4.z, hold4.w};
    float hn[4];
    unsigned short hi[4], lo[4];
    #pragma unroll
    for (int reg = 0; reg < 4; ++reg) {
      float r = 1.f / (1.f + expf(-(acc_r[reg] + bra[reg])));
      float z = 1.f / (1.f + expf(-(acc_z[reg] + bza[reg])));
      float n = tanhf(acc_gin[reg] + bia[reg] + r * (acc_ghn[reg] + bha[reg]));
      hn[reg] = (1.f - z) * n + z * ho[reg];
      hi[reg] = f2bf(hn[reg]);
      lo[reg] = f2bf(hn[reg] - bf2f(hi[reg]));
    }
    float4 hout = {hn[0], hn[1], hn[2], hn[3]};
    *(float4*)(h_wr + (size_t)b * HIDN + j) = hout;
    int kt2 = j >> 5, kr2 = j & 31;
    int ln2 = ((kr2 >> 3) << 4) | col, e2 = kr2 & 7;
    char* dst = Hsp_wr + ((size_t)((b >> 4) * 16 + kt2) * 2048 + ln2 * 16 + e2 * 2);
    uint2 Hp, Lp;
    Hp.x = (unsigned)hi[0] | ((unsigned)hi[1] << 16);
    Hp.y = (unsigned)hi[2] | ((unsigned)hi[3] << 16);
    Lp.x = (unsigned)lo[0] | ((unsigned)lo[1] << 16);
    Lp.y = (unsigned)lo[2] | ((unsigned)lo[3] << 16);
    *(uint2*)dst = Hp;
    *(uint2*)(dst + 1024) = Lp;
  }
}

// ---------- logits unit (r7 k_logits6 math; W from regs or streamed) ----------
__device__ __forceinline__ void logits_unit(
    int u, int t, int T, bool useReg,
    const short8 (&WH)[4][2], const short8 (&WL)[4][2],
    const char* __restrict__ Wsp, const char* __restrict__ Hsp,
    const float* __restrict__ bout, float* __restrict__ out_logits,
    unsigned long long* __restrict__ slots, char* lds, int lane, int wid) {
  f32x4 (*red2)[4][2][64] = (f32x4 (*)[4][2][64])lds;  // [wave][nb][mv][lane]
  int v0 = u * 32, vt = v0 >> 4;
  int sub = u & (NSUB - 1);

  f32x4 acc[4][2];
  #pragma unroll
  for (int nb = 0; nb < 4; ++nb)
    #pragma unroll
    for (int mv = 0; mv < 2; ++mv)
      acc[nb][mv] = (f32x4){0.f, 0.f, 0.f, 0.f};

  #pragma unroll 2
  for (int kk = 0; kk < 4; ++kk) {
    int kt = wid * 4 + kk;
    short8 ah[4], al[4], wh[2], wl[2];
    #pragma unroll
    for (int nb = 0; nb < 4; ++nb) {
      const char* q = Hsp + (size_t)(nb * 16 + kt) * 2048 + lane * 16;
      ah[nb] = *(const short8*)q;
      al[nb] = *(const short8*)(q + 1024);
    }
    if (useReg) {
      wh[0] = WH[kk][0]; wh[1] = WH[kk][1];
      wl[0] = WL[kk][0]; wl[1] = WL[kk][1];
    } else {
      #pragma unroll
      for (int mv = 0; mv < 2; ++mv) {
        const char* p = Wsp + (size_t)((vt + mv) * 16 + kt) * 2048 + lane * 16;
        wh[mv] = *(const short8*)p;
        wl[mv] = *(const short8*)(p + 1024);
      }
    }
    #pragma unroll
    for (int nb = 0; nb < 4; ++nb)
      #pragma unroll
      for (int mv = 0; mv < 2; ++mv)
        acc[nb][mv] = mfma3(ah[nb], al[nb], wh[mv], wl[mv], acc[nb][mv]);
  }

  #pragma unroll
  for (int nb = 0; nb < 4; ++nb)
    #pragma unroll
    for (int mv = 0; mv < 2; ++mv)
      red2[wid][nb][mv][lane] = acc[nb][mv];
  __syncthreads();

  int nb = wid;
  f32x4 sum[2];
  #pragma unroll
  for (int mv = 0; mv < 2; ++mv)
    sum[mv] = red2[0][nb][mv][lane] + red2[1][nb][mv][lane] +
              red2[2][nb][mv][lane] + red2[3][nb][mv][lane];

  int col = lane & 15, rg = lane >> 4;
  float bvv[2] = {bout[v0 + col], bout[v0 + 16 + col]};
  unsigned long long key[4] = {0ull, 0ull, 0ull, 0ull};

  #pragma unroll
  for (int mv = 0; mv < 2; ++mv) {
    int v = v0 + mv * 16 + col;
    #pragma unroll
    for (int reg = 0; reg < 4; ++reg) {
      float val = sum[mv][reg] + bvv[mv];
      int b = nb * 16 + rg * 4 + reg;
      __builtin_nontemporal_store(
          val, out_logits + ((size_t)b * T + t) * VOCABN + v);
      unsigned long long pk = ((unsigned long long)ordf(val) << 32) |
                              (unsigned long long)(0xFFFFFFFFu - (unsigned)v);
      key[reg] = (pk > key[reg]) ? pk : key[reg];
    }
  }
  #pragma unroll
  for (int m = 1; m < 16; m <<= 1) {
    #pragma unroll
    for (int reg = 0; reg < 4; ++reg) {
      unsigned long long o = __shfl_xor(key[reg], m, 64);
      key[reg] = (o > key[reg]) ? o : key[reg];
    }
  }
  if (col == 0) {
    #pragma unroll
    for (int reg = 0; reg < 4; ++reg) {
      int b = nb * 16 + rg * 4 + reg;
      atomicMax(slots + sub * BN + b, key[reg]);
    }
  }
}

// ---------- persistent cooperative kernel: all T steps ----------
__global__ __launch_bounds__(256, 2) void k_steps(
    const float* __restrict__ emb, const char* __restrict__ Wihsp,
    const char* __restrict__ Whhsp, const float* __restrict__ b_ih,
    const float* __restrict__ b_hh, const char* __restrict__ Wsp,
    const float* __restrict__ bout, float* __restrict__ hbuf,
    char* __restrict__ Hsp, unsigned long long* __restrict__ slots2,
    int* __restrict__ done, float* __restrict__ out_toks,
    float* __restrict__ out_logits, int T) {
  cg::grid_group grid = cg::this_grid();
  __shared__ __align__(16) char lds[4 * 4 * 2 * 64 * 16];  // 32 KB union
  int bid = blockIdx.x, tid = threadIdx.x, lane = tid & 63, wid = tid >> 6;
  bool hold = (bid >= GHBLK);

  // unit-1 W: loaded ONCE, register-resident across all T steps (hold blocks)
  short8 wh1[4][2], wl1[4][2];
  if (hold) {
    int vt1 = bid * 2;
    #pragma unroll
    for (int kk = 0; kk < 4; ++kk) {
      int kt = wid * 4 + kk;
      #pragma unroll
      for (int mv = 0; mv < 2; ++mv) {
        const char* p = Wsp + (size_t)((vt1 + mv) * 16 + kt) * 2048 + lane * 16;
        wh1[kk][mv] = *(const short8*)p;
        wl1[kk][mv] = *(const short8*)(p + 1024);
      }
    }
  }

  for (int t = 0; t < T; ++t) {
    const float* h_rd = hbuf + (size_t)(t & 1) * BN * HIDN;
    float* h_wr       = hbuf + (size_t)((t + 1) & 1) * BN * HIDN;
    const char* Hsp_rd = Hsp + (size_t)(t & 1) * 131072;
    char* Hsp_wr       = Hsp + (size_t)((t + 1) & 1) * 131072;
    const unsigned long long* s_rd = slots2 + ((t + 1) & 1) * NSUB * BN;
    unsigned long long* s_wr       = slots2 + (t & 1) * NSUB * BN;
    const int* drd = done + (t & 1) * BN;
    int* dwr       = done + ((t + 1) & 1) * BN;

    // ---- phase A: gates + GRU combine on blocks 0..127 ----
    if (bid < GHBLK)
      gh_body(bid, tid, lane, wid, lds, emb, Wihsp, Whhsp, b_ih, b_hh,
              h_rd, h_wr, Hsp_rd, Hsp_wr, s_rd, s_wr, drd, dwr, out_toks, t, T);
    grid.sync();

    // ---- phase B: logits (unit bid from regs if held; unit bid+NBLK streamed)
    logits_unit(bid, t, T, hold, wh1, wl1, Wsp, Hsp_wr, bout, out_logits,
                s_wr, lds, lane, wid);
    __syncthreads();
    logits_unit(bid + NBLK, t, T, false, wh1, wl1, Wsp, Hsp_wr, bout,
                out_logits, s_wr, lds, lane, wid);
    grid.sync();
  }

  // ---- final token (t = T-1) ----
  if (bid == 0 && tid < BN) {
    const unsigned long long* sl = slots2 + ((T - 1) & 1) * NSUB * BN;
    const int* dr = done + (T & 1) * BN;
    unsigned long long mx = 0ull;
    #pragma unroll
    for (int s = 0; s < NSUB; ++s) {
      unsigned long long v = sl[s * BN + tid];
      mx = (v > mx) ? v : mx;
    }
    int pred = decode_pred(mx);
    int iseos = (pred == EOSID) ? 1 : 0;
    int tok = (dr[tid] || iseos) ? 0 : pred;
    out_toks[(size_t)tid * T + (T - 1)] = (float)tok;
  }
}

// ---------- fallback kernels (r7 path) ----------
__global__ __launch_bounds__(256) void k_gh_fb(
    const float* __restrict__ emb, const char* __restrict__ Wihsp,
    const char* __restrict__ Whhsp, const float* __restrict__ b_ih,
    const float* __restrict__ b_hh, const float* __restrict__ h_rd,
    float* __restrict__ h_wr, const char* __restrict__ Hsp_rd,
    char* __restrict__ Hsp_wr, const unsigned long long* __restrict__ s_rd,
    unsigned long long* __restrict__ s_wr, const int* __restrict__ done_rd,
    int* __restrict__ done_wr, float* __restrict__ out_toks, int t, int T) {
  __shared__ __align__(16) char lds[64 + 3 * 4 * 256 * 4];
  int tid = threadIdx.x, lane = tid & 63, wid = tid >> 6;
  gh_body(blockIdx.x, tid, lane, wid, lds, emb, Wihsp, Whhsp, b_ih, b_hh,
          h_rd, h_wr, Hsp_rd, Hsp_wr, s_rd, s_wr, done_rd, done_wr,
          out_toks, t, T);
}

__global__ __launch_bounds__(256) void k_logits_fb(
    const char* __restrict__ Wsp, const char* __restrict__ Hsp,
    const float* __restrict__ bout, float* __restrict__ out_logits,
    unsigned long long* __restrict__ slots, int t, int T) {
  __shared__ __align__(16) char lds[4 * 4 * 2 * 64 * 16];
  int tid = threadIdx.x, lane = tid & 63, wid = tid >> 6;
  short8 dh[4][2], dl[4][2];
  logits_unit(blockIdx.x, t, T, false, dh, dl, Wsp, Hsp, bout, out_logits,
              slots, lds, lane, wid);
}

__global__ void k_final_fb(const unsigned long long* __restrict__ slots,
                           const int* __restrict__ done_rd,
                           float* __restrict__ out_toks, int T) {
  int b = threadIdx.x;
  if (b < BN) {
    unsigned long long mx = 0ull;
    #pragma unroll
    for (int s = 0; s < NSUB; ++s) {
      unsigned long long v = slots[s * BN + b];
      mx = (v > mx) ? v : mx;
    }
    int pred = decode_pred(mx);
    int iseos = (pred == EOSID) ? 1 : 0;
    int tok = (done_rd[b] || iseos) ? 0 : pred;
    out_toks[(size_t)b * T + (T - 1)] = (float)tok;
  }
}

// ---------- launch ----------
extern "C" void kernel_launch(void* const* d_in, const int* in_sizes, int n_in,
                              void* d_out, int out_size, void* d_ws, size_t ws_size,
                              hipStream_t stream) {
  const float* feat = (const float*)d_in[0];
  const float* emb  = (const float*)d_in[1];
  const float* W_ih = (const float*)d_in[2];
  const float* W_hh = (const float*)d_in[3];
  const float* b_ih = (const float*)d_in[4];
  const float* b_hh = (const float*)d_in[5];
  const float* Wout = (const float*)d_in[6];
  const float* bout = (const float*)d_in[7];

  int L = in_sizes[0] / (BN * HIDN);
  int T = out_size / (BN * (VOCABN + 1));
  if (T <= 0) T = 20;

  float* out_toks   = (float*)d_out;
  float* out_logits = (float*)d_out + (size_t)BN * T;

  char* w = (char*)d_ws;
  float* hbuf = (float*)w;  w += (size_t)2 * BN * HIDN * sizeof(float);
  int*   done = (int*)w;    w += (size_t)2 * BN * sizeof(int);
  w = (char*)(((uintptr_t)w + 511) & ~(uintptr_t)511);
  unsigned long long* slots2 = (unsigned long long*)w;   // 2 x NSUB x BN
  w += (size_t)2 * NSUB * BN * sizeof(unsigned long long);
  w = (char*)(((uintptr_t)w + 511) & ~(uintptr_t)511);
  char* Hsp   = w;          w += (size_t)2 * 4 * 16 * 2048;       // 2 x 128 KiB
  char* Wihsp = w;          w += (size_t)96 * 8 * 2048;           // 1.5 MiB
  char* Whhsp = w;          w += (size_t)96 * 16 * 2048;          // 3 MiB
  char* Wsp   = w;          w += (size_t)2000 * 16 * 2048;        // 62.5 MiB

  k_init<<<BN, 256, 0, stream>>>(feat, hbuf, L, done, Hsp);
  k_splitW<<<2000 * 16 / 4, 256, 0, stream>>>(Wout, Wsp, 4, 512);
  k_splitW<<<96 * 8 / 4, 256, 0, stream>>>(W_ih, Wihsp, 3, 256);
  k_splitW<<<96 * 16 / 4, 256, 0, stream>>>(W_hh, Whhsp, 4, 512);

  void* kargs[] = {(void*)&emb,  (void*)&Wihsp, (void*)&Whhsp, (void*)&b_ih,
                   (void*)&b_hh, (void*)&Wsp,   (void*)&bout,  (void*)&hbuf,
                   (void*)&Hsp,  (void*)&slots2, (void*)&done, (void*)&out_toks,
                   (void*)&out_logits, (void*)&T};
  hipError_t err = hipLaunchCooperativeKernel(
      (const void*)k_steps, dim3(NBLK), dim3(256), kargs, 0, stream);

  if (err != hipSuccess) {
    // fallback: r7 multi-launch path
    for (int t = 0; t < T; ++t) {
      const float* h_rd = hbuf + (size_t)(t & 1) * BN * HIDN;
      float* h_wr       = hbuf + (size_t)((t + 1) & 1) * BN * HIDN;
      const char* Hsp_rd = Hsp + (size_t)(t & 1) * 131072;
      char* Hsp_wr       = Hsp + (size_t)((t + 1) & 1) * 131072;
      const unsigned long long* s_rd = slots2 + ((t + 1) & 1) * NSUB * BN;
      unsigned long long* s_wr       = slots2 + (t & 1) * NSUB * BN;
      const int* drd = done + (t & 1) * BN;
      int* dwr       = done + ((t + 1) & 1) * BN;
      k_gh_fb<<<128, 256, 0, stream>>>(emb, Wihsp, Whhsp, b_ih, b_hh, h_rd,
                                       h_wr, Hsp_rd, Hsp_wr, s_rd, s_wr, drd,
                                       dwr, out_toks, t, T);
      k_logits_fb<<<VOCABN / 32, 256, 0, stream>>>(Wsp, Hsp_wr, bout,
                                                   out_logits, s_wr, t, T);
    }
    k_final_fb<<<1, 64, 0, stream>>>(slots2 + ((T - 1) & 1) * NSUB * BN,
                                     done + (T & 1) * BN, out_toks, T);
  }
}

// Round 11
// 591.361 us; speedup vs baseline: 4.5383x; 4.5383x over previous
//
#include <hip/hip_runtime.h>
#include <stdint.h>

#define VOCABN 32000
#define EMBEDN 256
#define HIDN   512
#define BN     64
#define SOSID  1
#define EOSID  2
#define NSUB   8   // argmax sub-slots to spread atomic contention

typedef __attribute__((ext_vector_type(8))) short short8;
typedef __attribute__((ext_vector_type(4))) float f32x4;

// ---------- helpers ----------
__device__ __forceinline__ unsigned ordf(float f) {
  unsigned u = __float_as_uint(f);
  return (u & 0x80000000u) ? ~u : (u | 0x80000000u);
}
__device__ __forceinline__ int decode_pred(unsigned long long pk) {
  return (int)(0xFFFFFFFFu - (unsigned)(pk & 0xFFFFFFFFull));
}
__device__ __forceinline__ unsigned short f2bf(float x) {  // RNE f32->bf16
  unsigned u = __float_as_uint(x);
  unsigned r = (u + 0x7FFFu + ((u >> 16) & 1u)) >> 16;
  return (unsigned short)r;
}
__device__ __forceinline__ float bf2f(unsigned short h) {
  return __uint_as_float(((unsigned)h) << 16);
}
// acc += Ahi*Bhi + Ahi*Blo + Alo*Bhi   (bf16x3 split product)
__device__ __forceinline__ f32x4 mfma3(short8 ah, short8 al, short8 bh, short8 bl,
                                       f32x4 acc) {
  acc = __builtin_amdgcn_mfma_f32_16x16x32_bf16(ah, bh, acc, 0, 0, 0);
  acc = __builtin_amdgcn_mfma_f32_16x16x32_bf16(ah, bl, acc, 0, 0, 0);
  acc = __builtin_amdgcn_mfma_f32_16x16x32_bf16(al, bh, acc, 0, 0, 0);
  return acc;
}

// ---------- init: h0 = mean(features), fp32 + bf16 hi/lo fragment split ----------
__global__ void k_init(const float* __restrict__ feat, float* __restrict__ h0,
                       int L, int* __restrict__ done, char* __restrict__ Hsp0) {
  int b = blockIdx.x, tid = threadIdx.x;
  float inv = 1.0f / (float)L;
  for (int j = tid; j < HIDN; j += 256) {
    const float* p = feat + (size_t)b * L * HIDN + j;
    float s = 0.f;
    for (int l = 0; l < L; ++l) s += p[(size_t)l * HIDN];
    float hv = s * inv;
    h0[b * HIDN + j] = hv;
    unsigned short hi = f2bf(hv);
    unsigned short lo = f2bf(hv - bf2f(hi));
    int bt = b >> 4, col = b & 15, kt = j >> 5, kr = j & 31;
    int ln = ((kr >> 3) << 4) | col, e = kr & 7;
    size_t off = (size_t)(bt * 16 + kt) * 2048 + ln * 16 + e * 2;
    *(unsigned short*)(Hsp0 + off) = hi;
    *(unsigned short*)(Hsp0 + off + 1024) = lo;
  }
  if (b == 0 && tid < 2 * BN) done[tid] = 0;
}

// ---------- generic W split into MFMA-fragment-ordered bf16 hi/lo tiles ----------
// tile id = vt*(K/32)+kt; elem j of lane l = W[vt*16+(l&15)][kt*32+(l>>4)*8+j]
__global__ __launch_bounds__(256) void k_splitW(const float* __restrict__ W,
                                                char* __restrict__ Wsp,
                                                int ktshift, int K) {
  int tid = threadIdx.x, lane = tid & 63, tl = tid >> 6;
  int tile = blockIdx.x * 4 + tl;
  int vt = tile >> ktshift, kt = tile & ((1 << ktshift) - 1);
  int v = vt * 16 + (lane & 15);
  int k0 = kt * 32 + ((lane >> 4) << 3);
  const float* src = W + (size_t)v * K + k0;
  float xv[8];
  *(float4*)&xv[0] = *(const float4*)src;
  *(float4*)&xv[4] = *(const float4*)(src + 4);
  unsigned short h[8], l[8];
  #pragma unroll
  for (int i = 0; i < 8; ++i) {
    h[i] = f2bf(xv[i]);
    l[i] = f2bf(xv[i] - bf2f(h[i]));
  }
  uint4 H, Lw;
  H.x = (unsigned)h[0] | ((unsigned)h[1] << 16);
  H.y = (unsigned)h[2] | ((unsigned)h[3] << 16);
  H.z = (unsigned)h[4] | ((unsigned)h[5] << 16);
  H.w = (unsigned)h[6] | ((unsigned)h[7] << 16);
  Lw.x = (unsigned)l[0] | ((unsigned)l[1] << 16);
  Lw.y = (unsigned)l[2] | ((unsigned)l[3] << 16);
  Lw.z = (unsigned)l[4] | ((unsigned)l[5] << 16);
  Lw.w = (unsigned)l[6] | ((unsigned)l[7] << 16);
  char* dst = Wsp + (size_t)tile * 2048 + lane * 16;
  *(uint4*)dst = H;
  *(uint4*)(dst + 1024) = Lw;
}

// ---------- fused gates + GRU combine (all-MFMA, bf16x3) ----------
// 128 blocks (jt=bid>>2 over 32 j-tiles, bt=bid&3 over 4 b-tiles) x 4 waves.
// 24 K-units (gi: 8 of K=256, gh: 16 of K=512) split 6 per wave; LDS reduce;
// wave 0 does the register-local GRU combine + h/Hsp writes.
__global__ __launch_bounds__(256) void k_gh(
    const float* __restrict__ emb, const char* __restrict__ Wihsp,
    const char* __restrict__ Whhsp, const float* __restrict__ b_ih,
    const float* __restrict__ b_hh, const float* __restrict__ h_rd,
    float* __restrict__ h_wr, const char* __restrict__ Hsp_rd,
    char* __restrict__ Hsp_wr,
    const unsigned long long* __restrict__ s_rd,
    unsigned long long* __restrict__ s_wr,
    const int* __restrict__ done_rd, int* __restrict__ done_wr,
    float* __restrict__ out_toks, int t, int T) {
  __shared__ int preds[16];
  __shared__ float red[3][4][256];
  int tid = threadIdx.x, lane = tid & 63, wid = tid >> 6;
  int jt = blockIdx.x >> 2, bt = blockIdx.x & 3;

  if (tid < 16) {
    int pr = SOSID;
    if (t) {
      unsigned long long mx = 0ull;
      #pragma unroll
      for (int s = 0; s < NSUB; ++s) {
        unsigned long long v = s_rd[s * BN + bt * 16 + tid];
        mx = (v > mx) ? v : mx;
      }
      pr = decode_pred(mx);
    }
    preds[tid] = pr;
  }
  if (blockIdx.x == 0) {
    s_wr[tid] = 0ull;                      // zero this step's argmax buffer
    s_wr[256 + tid] = 0ull;
    if (t >= 1 && tid < BN) {
      unsigned long long mx = 0ull;
      #pragma unroll
      for (int s = 0; s < NSUB; ++s) {
        unsigned long long v = s_rd[s * BN + tid];
        mx = (v > mx) ? v : mx;
      }
      int pred = decode_pred(mx);
      int iseos = (pred == EOSID) ? 1 : 0;
      int dold = done_rd[tid];
      out_toks[(size_t)tid * T + (t - 1)] = (float)((dold | iseos) ? 0 : pred);
      done_wr[tid] = dold | iseos;
    }
  }
  __syncthreads();

  int col = lane & 15, rg = lane >> 4;
  int xrow = preds[col];
  f32x4 acc_r = {0.f, 0.f, 0.f, 0.f}, acc_z = {0.f, 0.f, 0.f, 0.f};
  f32x4 acc_gin = {0.f, 0.f, 0.f, 0.f}, acc_ghn = {0.f, 0.f, 0.f, 0.f};

  #pragma unroll
  for (int u = 0; u < 6; ++u) {
    int g = wid * 6 + u;
    if (g < 8) {
      float xv[8];
      const float* src = emb + (size_t)xrow * EMBEDN + g * 32 + rg * 8;
      *(float4*)&xv[0] = *(const float4*)src;
      *(float4*)&xv[4] = *(const float4*)(src + 4);
      unsigned short hi[8], lo[8];
      #pragma unroll
      for (int i = 0; i < 8; ++i) {
        hi[i] = f2bf(xv[i]);
        lo[i] = f2bf(xv[i] - bf2f(hi[i]));
      }
      short8 xh, xl;
      #pragma unroll
      for (int i = 0; i < 8; ++i) { xh[i] = (short)hi[i]; xl[i] = (short)lo[i]; }
      const char* pr_ = Wihsp + (size_t)((jt) * 8 + g) * 2048 + lane * 16;
      const char* pz_ = Wihsp + (size_t)((32 + jt) * 8 + g) * 2048 + lane * 16;
      const char* pn_ = Wihsp + (size_t)((64 + jt) * 8 + g) * 2048 + lane * 16;
      acc_r = mfma3(*(const short8*)pr_, *(const short8*)(pr_ + 1024), xh, xl, acc_r);
      acc_z = mfma3(*(const short8*)pz_, *(const short8*)(pz_ + 1024), xh, xl, acc_z);
      acc_gin = mfma3(*(const short8*)pn_, *(const short8*)(pn_ + 1024), xh, xl, acc_gin);
    } else {
      int kt = g - 8;
      const char* bq = Hsp_rd + (size_t)(bt * 16 + kt) * 2048 + lane * 16;
      short8 hh = *(const short8*)bq;
      short8 hl = *(const short8*)(bq + 1024);
      const char* pr_ = Whhsp + (size_t)((jt) * 16 + kt) * 2048 + lane * 16;
      const char* pz_ = Whhsp + (size_t)((32 + jt) * 16 + kt) * 2048 + lane * 16;
      const char* pn_ = Whhsp + (size_t)((64 + jt) * 16 + kt) * 2048 + lane * 16;
      acc_r = mfma3(*(const short8*)pr_, *(const short8*)(pr_ + 1024), hh, hl, acc_r);
      acc_z = mfma3(*(const short8*)pz_, *(const short8*)(pz_ + 1024), hh, hl, acc_z);
      acc_ghn = mfma3(*(const short8*)pn_, *(const short8*)(pn_ + 1024), hh, hl, acc_ghn);
    }
  }

  if (wid) {
    *(f32x4*)&red[wid - 1][0][lane * 4] = acc_r;
    *(f32x4*)&red[wid - 1][1][lane * 4] = acc_z;
    *(f32x4*)&red[wid - 1][2][lane * 4] = acc_gin;
    *(f32x4*)&red[wid - 1][3][lane * 4] = acc_ghn;
  }
  __syncthreads();
  if (wid == 0) {
    #pragma unroll
    for (int w = 0; w < 3; ++w) {
      acc_r += *(f32x4*)&red[w][0][lane * 4];
      acc_z += *(f32x4*)&red[w][1][lane * 4];
      acc_gin += *(f32x4*)&red[w][2][lane * 4];
      acc_ghn += *(f32x4*)&red[w][3][lane * 4];
    }
    int j0 = jt * 16, j = j0 + rg * 4;
    int b = bt * 16 + col;
    float4 bir = *(const float4*)(b_ih + j);
    float4 bhr = *(const float4*)(b_hh + j);
    float4 biz = *(const float4*)(b_ih + 512 + j);
    float4 bhz = *(const float4*)(b_hh + 512 + j);
    float4 bin = *(const float4*)(b_ih + 1024 + j);
    float4 bhn = *(const float4*)(b_hh + 1024 + j);
    float bra[4] = {bir.x + bhr.x, bir.y + bhr.y, bir.z + bhr.z, bir.w + bhr.w};
    float bza[4] = {biz.x + bhz.x, biz.y + bhz.y, biz.z + bhz.z, biz.w + bhz.w};
    float bia[4] = {bin.x, bin.y, bin.z, bin.w};
    float bha[4] = {bhn.x, bhn.y, bhn.z, bhn.w};
    float4 hold = *(const float4*)(h_rd + (size_t)b * HIDN + j);
    float ho[4] = {hold.x, hold.y, hold.z, hold.w};
    float hn[4];
    unsigned short hi[4], lo[4];
    #pragma unroll
    for (int reg = 0; reg < 4; ++reg) {
      float r = 1.f / (1.f + expf(-(acc_r[reg] + bra[reg])));
      float z = 1.f / (1.f + expf(-(acc_z[reg] + bza[reg])));
      float n = tanhf(acc_gin[reg] + bia[reg] + r * (acc_ghn[reg] + bha[reg]));
      hn[reg] = (1.f - z) * n + z * ho[reg];
      hi[reg] = f2bf(hn[reg]);
      lo[reg] = f2bf(hn[reg] - bf2f(hi[reg]));
    }
    float4 hout = {hn[0], hn[1], hn[2], hn[3]};
    *(float4*)(h_wr + (size_t)b * HIDN + j) = hout;
    int kt2 = j >> 5, kr2 = j & 31;
    int ln2 = ((kr2 >> 3) << 4) | col, e2 = kr2 & 7;
    char* dst = Hsp_wr + ((size_t)((b >> 4) * 16 + kt2) * 2048 + ln2 * 16 + e2 * 2);
    uint2 Hp, Lp;
    Hp.x = (unsigned)hi[0] | ((unsigned)hi[1] << 16);
    Hp.y = (unsigned)hi[2] | ((unsigned)hi[3] << 16);
    Lp.x = (unsigned)lo[0] | ((unsigned)lo[1] << 16);
    Lp.y = (unsigned)lo[2] | ((unsigned)lo[3] << 16);
    *(uint2*)dst = Hp;
    *(uint2*)(dst + 1024) = Lp;
  }
}

// ---------- logits: bf16x3 MFMA, K-split 4 ways, ALL-WAVE parallel epilogue ----
// 1000 blocks x 4 waves. Compute: wave wid = K-quarter (4 kt) x 32v x 64b
// (every W/H tile read by exactly one wave). Reduce: all waves dump partials
// to LDS; after barrier wave wid owns b-tile nb=wid: sums 4 partials, adds
// bias, stores its 16b x 32v slice (coalesced 64B runs) + argmax atomics.
__global__ __launch_bounds__(256) void k_logits6(
    const char* __restrict__ Wsp, const char* __restrict__ Hsp,
    const float* __restrict__ bout, float* __restrict__ out_logits,
    unsigned long long* __restrict__ slots, int t, int T) {
  __shared__ __align__(16) f32x4 red[4][4][2][64];  // [wave][nb][mv][lane] 32KB
  int tid = threadIdx.x, lane = tid & 63, wid = tid >> 6;
  int v0 = blockIdx.x * 32, vt = v0 >> 4;
  int sub = blockIdx.x & (NSUB - 1);

  f32x4 acc[4][2];  // [nb][mv]
  #pragma unroll
  for (int nb = 0; nb < 4; ++nb)
    #pragma unroll
    for (int mv = 0; mv < 2; ++mv)
      acc[nb][mv] = (f32x4){0.f, 0.f, 0.f, 0.f};

  #pragma unroll 2
  for (int kk = 0; kk < 4; ++kk) {
    int kt = wid * 4 + kk;
    short8 ah[4], al[4], wh[2], wl[2];
    #pragma unroll
    for (int nb = 0; nb < 4; ++nb) {
      const char* q = Hsp + (size_t)(nb * 16 + kt) * 2048 + lane * 16;
      ah[nb] = *(const short8*)q;
      al[nb] = *(const short8*)(q + 1024);
    }
    #pragma unroll
    for (int mv = 0; mv < 2; ++mv) {
      const char* p = Wsp + (size_t)((vt + mv) * 16 + kt) * 2048 + lane * 16;
      wh[mv] = *(const short8*)p;
      wl[mv] = *(const short8*)(p + 1024);
    }
    #pragma unroll
    for (int nb = 0; nb < 4; ++nb)
      #pragma unroll
      for (int mv = 0; mv < 2; ++mv)
        acc[nb][mv] = mfma3(ah[nb], al[nb], wh[mv], wl[mv], acc[nb][mv]);
  }

  // all waves dump partials
  #pragma unroll
  for (int nb = 0; nb < 4; ++nb)
    #pragma unroll
    for (int mv = 0; mv < 2; ++mv)
      red[wid][nb][mv][lane] = acc[nb][mv];
  __syncthreads();

  // wave wid owns b-tile nb = wid
  int nb = wid;
  f32x4 sum[2];
  #pragma unroll
  for (int mv = 0; mv < 2; ++mv)
    sum[mv] = red[0][nb][mv][lane] + red[1][nb][mv][lane] +
              red[2][nb][mv][lane] + red[3][nb][mv][lane];

  int col = lane & 15, rg = lane >> 4;
  float bvv[2] = {bout[v0 + col], bout[v0 + 16 + col]};
  unsigned long long key[4] = {0ull, 0ull, 0ull, 0ull};

  #pragma unroll
  for (int mv = 0; mv < 2; ++mv) {
    int v = v0 + mv * 16 + col;
    #pragma unroll
    for (int reg = 0; reg < 4; ++reg) {
      float val = sum[mv][reg] + bvv[mv];
      int b = nb * 16 + rg * 4 + reg;
      __builtin_nontemporal_store(
          val, out_logits + ((size_t)b * T + t) * VOCABN + v);
      unsigned long long pk = ((unsigned long long)ordf(val) << 32) |
                              (unsigned long long)(0xFFFFFFFFu - (unsigned)v);
      key[reg] = (pk > key[reg]) ? pk : key[reg];
    }
  }
  // reduce each key over the 16 col-lanes of its rg group
  #pragma unroll
  for (int m = 1; m < 16; m <<= 1) {
    #pragma unroll
    for (int reg = 0; reg < 4; ++reg) {
      unsigned long long o = __shfl_xor(key[reg], m, 64);
      key[reg] = (o > key[reg]) ? o : key[reg];
    }
  }
  if (col == 0) {
    #pragma unroll
    for (int reg = 0; reg < 4; ++reg) {
      int b = nb * 16 + rg * 4 + reg;
      atomicMax(slots + sub * BN + b, key[reg]);
    }
  }
}

// ---------- final token (t = T-1) ----------
__global__ void k_final(const unsigned long long* __restrict__ slots,
                        const int* __restrict__ done_rd,
                        float* __restrict__ out_toks, int T) {
  int b = threadIdx.x;
  if (b < BN) {
    unsigned long long mx = 0ull;
    #pragma unroll
    for (int s = 0; s < NSUB; ++s) {
      unsigned long long v = slots[s * BN + b];
      mx = (v > mx) ? v : mx;
    }
    int pred = decode_pred(mx);
    int iseos = (pred == EOSID) ? 1 : 0;
    int tok = (done_rd[b] || iseos) ? 0 : pred;
    out_toks[(size_t)b * T + (T - 1)] = (float)tok;
  }
}

// ---------- launch ----------
extern "C" void kernel_launch(void* const* d_in, const int* in_sizes, int n_in,
                              void* d_out, int out_size, void* d_ws, size_t ws_size,
                              hipStream_t stream) {
  const float* feat = (const float*)d_in[0];
  const float* emb  = (const float*)d_in[1];
  const float* W_ih = (const float*)d_in[2];
  const float* W_hh = (const float*)d_in[3];
  const float* b_ih = (const float*)d_in[4];
  const float* b_hh = (const float*)d_in[5];
  const float* Wout = (const float*)d_in[6];
  const float* bout = (const float*)d_in[7];

  int L = in_sizes[0] / (BN * HIDN);
  int T = out_size / (BN * (VOCABN + 1));
  if (T <= 0) T = 20;

  float* out_toks   = (float*)d_out;
  float* out_logits = (float*)d_out + (size_t)BN * T;

  char* w = (char*)d_ws;
  float* hbuf = (float*)w;  w += (size_t)2 * BN * HIDN * sizeof(float);
  int*   done = (int*)w;    w += (size_t)2 * BN * sizeof(int);
  w = (char*)(((uintptr_t)w + 511) & ~(uintptr_t)511);
  unsigned long long* slots2 = (unsigned long long*)w;   // 2 x NSUB x BN
  w += (size_t)2 * NSUB * BN * sizeof(unsigned long long);
  w = (char*)(((uintptr_t)w + 511) & ~(uintptr_t)511);
  char* Hsp   = w;          w += (size_t)2 * 4 * 16 * 2048;       // 2 x 128 KiB
  char* Wihsp = w;          w += (size_t)96 * 8 * 2048;           // 1.5 MiB
  char* Whhsp = w;          w += (size_t)96 * 16 * 2048;          // 3 MiB
  char* Wsp   = w;          w += (size_t)2000 * 16 * 2048;        // 62.5 MiB

  k_init<<<BN, 256, 0, stream>>>(feat, hbuf, L, done, Hsp);
  k_splitW<<<2000 * 16 / 4, 256, 0, stream>>>(Wout, Wsp, 4, 512);
  k_splitW<<<96 * 8 / 4, 256, 0, stream>>>(W_ih, Wihsp, 3, 256);
  k_splitW<<<96 * 16 / 4, 256, 0, stream>>>(W_hh, Whhsp, 4, 512);

  for (int t = 0; t < T; ++t) {
    const float* h_rd = hbuf + (size_t)(t & 1) * BN * HIDN;
    float* h_wr       = hbuf + (size_t)((t + 1) & 1) * BN * HIDN;
    const char* Hsp_rd = Hsp + (size_t)(t & 1) * 131072;
    char* Hsp_wr       = Hsp + (size_t)((t + 1) & 1) * 131072;
    const unsigned long long* s_rd = slots2 + ((t + 1) & 1) * NSUB * BN;
    unsigned long long* s_wr       = slots2 + (t & 1) * NSUB * BN;
    const int* drd = done + (t & 1) * BN;
    int* dwr       = done + ((t + 1) & 1) * BN;

    k_gh<<<128, 256, 0, stream>>>(emb, Wihsp, Whhsp, b_ih, b_hh, h_rd, h_wr,
                                  Hsp_rd, Hsp_wr, s_rd, s_wr, drd, dwr,
                                  out_toks, t, T);
    k_logits6<<<VOCABN / 32, 256, 0, stream>>>(Wsp, Hsp_wr, bout, out_logits,
                                               s_wr, t, T);
  }
  k_final<<<1, 64, 0, stream>>>(slots2 + ((T - 1) & 1) * NSUB * BN,
                                done + (T & 1) * BN, out_toks, T);
}